// Round 7
// baseline (379.270 us; speedup 1.0000x reference)
//
#include <hip/hip_runtime.h>
#include <hip/hip_bf16.h>

#define N_ROWS 262144
#define D_IN 162
#define K_DIM 30
#define ROWS 32          // rows per block

using bf16_t = __hip_bfloat16;
typedef __attribute__((ext_vector_type(8))) short bf16x8;
typedef __attribute__((ext_vector_type(4))) float f32x4;

// byte offset into the swizzled LDS tile: row stride 512 B, col in bf16 elems.
// XOR of (row&7) into byte bits 4-6 spreads 8 consecutive rows across 8
// distinct 16B slots.
__device__ __forceinline__ int swz_byte(int row, int col) {
  int b = (row << 9) + (col << 1);
  return b ^ ((row & 7) << 4);
}

__device__ __forceinline__ uint32_t bf16b(float x) {
  return (uint32_t)__builtin_bit_cast(unsigned short, __float2bfloat16(x));
}
__device__ __forceinline__ uint32_t pack2(float lo, float hi) {
  return bf16b(lo) | (bf16b(hi) << 16);
}
__device__ __forceinline__ float unpk_lo(uint32_t p) {
  return __bfloat162float(__builtin_bit_cast(__hip_bfloat16, (unsigned short)(p & 0xffff)));
}
__device__ __forceinline__ float unpk_hi(uint32_t p) {
  return __bfloat162float(__builtin_bit_cast(__hip_bfloat16, (unsigned short)(p >> 16)));
}

// single-instruction transcendentals (rel err ~1e-5 vs 2e-2 threshold)
__device__ __forceinline__ float fexp2(float x) { return __builtin_amdgcn_exp2f(x); }
__device__ __forceinline__ float flog2(float x) { return __builtin_amdgcn_logf(x); }
__device__ __forceinline__ float frcp (float x) { return __builtin_amdgcn_rcpf(x); }

__device__ __forceinline__ float sp_fast(float x) {        // softplus
  float e = fexp2(fabsf(x) * -1.44269504f);
  return fmaxf(x, 0.f) + 0.69314718f * flog2(1.f + e);
}
__device__ __forceinline__ float sigmoid_fast(float x) {
  return frcp(1.f + fexp2(x * -1.44269504f));
}

// ---------------- weight packing: fp32 [K][N] -> bf16 [kb][Np][32] ------------
__global__ void pack_b_kernel(const float* __restrict__ src, bf16_t* __restrict__ dst,
                              int K, int N, int Np, int KB) {
  int idx = blockIdx.x * 256 + threadIdx.x;
  int total = KB * Np * 32;
  if (idx >= total) return;
  int ks = idx & 31;
  int n  = (idx >> 5) % Np;
  int kb = idx / (32 * Np);
  int k  = kb * 32 + ks;
  float v = (k < K && n < N) ? src[k * N + n] : 0.f;
  dst[idx] = __float2bfloat16(v);
}

// Wa/Wb interleaved: out-col 2j = Wa[:,j], 2j+1 = Wb[:,j]
__global__ void pack_ab_kernel(const float* __restrict__ Wa, const float* __restrict__ Wb,
                               bf16_t* __restrict__ dst) {
  int idx = blockIdx.x * 256 + threadIdx.x;
  if (idx >= 8 * 64 * 32) return;
  int ks = idx & 31;
  int n  = (idx >> 5) & 63;
  int kb = idx >> 11;
  int k  = kb * 32 + ks;
  int j = n >> 1, s = n & 1;
  float v = (j < K_DIM) ? (s ? Wb[k * K_DIM + j] : Wa[k * K_DIM + j]) : 0.f;
  dst[idx] = __float2bfloat16(v);
}

// ---------------- weight fragment load (one kb, NMO out-col groups) -----------
template<int NP, int NMO>
__device__ __forceinline__ void wload(const bf16_t* __restrict__ Wp, int kb, int ocBase,
                                      int lr, int lg, bf16x8 (&out)[NMO]) {
#pragma unroll
  for (int mo = 0; mo < NMO; ++mo)
    out[mo] = *reinterpret_cast<const bf16x8*>(
        Wp + ((kb * NP + ocBase + 16 * mo + lr) << 5) + 8 * lg);
}

// ---------------- swapped-operand GEMM: read full tile into acc ---------------
// (no epilogue here: caller barriers, then writes in-place)
template<int KB, int NP, int NMO>
__device__ __forceinline__ void gemm_direct(const uint8_t* lds, int srcOff,
                                            const bf16_t* __restrict__ Wp, int ocBase,
                                            int lr, int lg, f32x4 (&acc)[NMO][2]) {
  int bE[2], bO[2];   // even/odd-kb bases (128B pair-steps commute with row-XOR)
#pragma unroll
  for (int nr = 0; nr < 2; ++nr) {
    bE[nr] = srcOff + swz_byte(16 * nr + lr, 8 * lg);
    bO[nr] = srcOff + swz_byte(16 * nr + lr, 32 + 8 * lg);
  }
#pragma unroll
  for (int kb = 0; kb < KB; ++kb) {
    bf16x8 wf[NMO];
    wload<NP, NMO>(Wp, kb, ocBase, lr, lg, wf);
    bf16x8 hf[2];
#pragma unroll
    for (int nr = 0; nr < 2; ++nr) {
      int base = (kb & 1) ? bO[nr] : bE[nr];
      hf[nr] = *reinterpret_cast<const bf16x8*>(lds + base + (kb >> 1) * 128);
    }
#pragma unroll
    for (int mo = 0; mo < NMO; ++mo)
#pragma unroll
      for (int nr = 0; nr < 2; ++nr)
        acc[mo][nr] = __builtin_amdgcn_mfma_f32_16x16x32_bf16(wf[mo], hf[nr], acc[mo][nr], 0, 0, 0);
  }
}

template<int NMO>
__device__ __forceinline__ void acc_bias_init(const float* __restrict__ bias, int ocBase,
                                              int lg, f32x4 (&acc)[NMO][2]) {
#pragma unroll
  for (int mo = 0; mo < NMO; ++mo) {
    float4 bv = *reinterpret_cast<const float4*>(bias + ocBase + 16 * mo + 4 * lg);
    f32x4 t = {bv.x, bv.y, bv.z, bv.w};
#pragma unroll
    for (int nr = 0; nr < 2; ++nr) acc[mo][nr] = t;
  }
}

// relu -> packed bf16x4 -> one ds_write_b64 per fragment
template<int NMO>
__device__ __forceinline__ void epi_relu_store(uint8_t* lds, int dstOff, int ocBase,
                                               int lr, int lg, f32x4 (&acc)[NMO][2]) {
#pragma unroll
  for (int mo = 0; mo < NMO; ++mo)
#pragma unroll
    for (int nr = 0; nr < 2; ++nr) {
      int row = 16 * nr + lr;
      int col = ocBase + 16 * mo + 4 * lg;
      float x0 = fmaxf(acc[mo][nr][0], 0.f), x1 = fmaxf(acc[mo][nr][1], 0.f);
      float x2 = fmaxf(acc[mo][nr][2], 0.f), x3 = fmaxf(acc[mo][nr][3], 0.f);
      uint2 p; p.x = pack2(x0, x1); p.y = pack2(x2, x3);
      *reinterpret_cast<uint2*>(lds + dstOff + swz_byte(row, col)) = p;
    }
}

// ---------------- fused scan + fragment build ---------------------------------
// Redundant per-lane stick-breaking over one row's v[0..28] (vbuf fp32 stride 33).
// Returns the bf16 B-fragment for k-window [8*LG, 8*LG+8). piPair != null (one
// lane-group only) additionally writes bf16 pi pairs to piT.
template<int LG>
__device__ __forceinline__ bf16x8 scan_frag(const float* __restrict__ vrow,
                                            uint8_t* __restrict__ piPair) {
  float ex = 1.f, hold = 0.f;
  uint32_t pk0 = 0, pk1 = 0, pk2 = 0, pk3 = 0;
#pragma unroll
  for (int j = 0; j < 32; ++j) {
    float pi;
    if (j < K_DIM - 1)       { float vj = vrow[j]; pi = vj * ex; ex *= (1.f - vj); }
    else if (j == K_DIM - 1)   pi = ex;      // v_K forced to 1
    else                       pi = 0.f;     // pad K->32
    if (j & 1) {
      uint32_t p = pack2(hold, pi);
      if (piPair != nullptr && j < K_DIM)
        *reinterpret_cast<uint32_t*>(piPair + (j - 1) * 2) = p;
      if (j >= 8 * LG && j < 8 * LG + 8) {
        switch ((j - 8 * LG) >> 1) {         // compile-time in unrolled loop
          case 0: pk0 = p; break; case 1: pk1 = p; break;
          case 2: pk2 = p; break; default: pk3 = p;
        }
      }
    } else hold = pi;
  }
  uint4 t = make_uint4(pk0, pk1, pk2, pk3);
  return __builtin_bit_cast(bf16x8, t);
}

// ---------------- fused forward ------------------------------------------------
// LDS: ONE 16KB swizzled tile [0,16384) reused in-place: Yh -> h1 -> h2 -> vbuf -> d.
// piT bf16 [32][40] at [16384, 18944). vbuf = fp32 stride-33 in tile bytes [0,4224).
#define OFF_PI 16384

__launch_bounds__(256, 8)
__global__ void usdn_fused(const float* __restrict__ Yh, const float* __restrict__ u,
                           const float* __restrict__ b1, const float* __restrict__ b2,
                           const float* __restrict__ ba, const float* __restrict__ bb,
                           const float* __restrict__ bd1, const float* __restrict__ bd2,
                           const bf16_t* __restrict__ Wp1, const bf16_t* __restrict__ Wp2,
                           const bf16_t* __restrict__ Wpab, const bf16_t* __restrict__ Wpd1,
                           const bf16_t* __restrict__ Wpd2,
                           float* __restrict__ outRecon, float* __restrict__ outAlpha,
                           float* __restrict__ outBeta, float* __restrict__ outPi) {
  __shared__ __align__(16) uint8_t lds[18944];

  const int tid = threadIdx.x;
  const int w  = tid >> 6;
  const int l  = tid & 63;
  const int lr = l & 15;
  const int lg = l >> 4;
  const int r0 = blockIdx.x * ROWS;

  // ---- stage Yh tile (32 x 162 fp32) -> tile bf16 cols 0..191 (two reg batches)
  {
    const int srow = tid >> 3, sl8 = tid & 7;
    const float2* src = reinterpret_cast<const float2*>(Yh + (size_t)(r0 + srow) * D_IN);
#pragma unroll
    for (int h = 0; h < 2; ++h) {
      float2 sv[6];
#pragma unroll
      for (int it = 0; it < 6; ++it) {
        int f2 = sl8 + (h * 6 + it) * 8;
        if (f2 < 81) sv[it] = src[f2];
      }
#pragma unroll
      for (int it = 0; it < 6; ++it) {
        int f2 = sl8 + (h * 6 + it) * 8;
        uint32_t p = 0;
        if (f2 < 81) p = pack2(sv[it].x, sv[it].y);
        if (f2 < 96) *reinterpret_cast<uint32_t*>(lds + swz_byte(srow, f2 * 2)) = p;
      }
    }
  }
  __syncthreads();                                   // S1

  // ---- GEMM1: h1 = relu(W1^T x^T + b1), K=192, IN-PLACE
  {
    f32x4 acc[4][2];
    acc_bias_init<4>(b1, w * 64, lg, acc);
    gemm_direct<6, 256, 4>(lds, 0, Wp1, w * 64, lr, lg, acc);
    __syncthreads();                                 // S2: all Yh reads done
    epi_relu_store<4>(lds, 0, w * 64, lr, lg, acc);
  }
  __syncthreads();                                   // S3

  // ---- GEMM2: h2 = relu(W2^T h1^T + b2), K=256, IN-PLACE
  {
    f32x4 acc[4][2];
    acc_bias_init<4>(b2, w * 64, lg, acc);
    gemm_direct<8, 256, 4>(lds, 0, Wp2, w * 64, lr, lg, acc);
    __syncthreads();                                 // S4: all h1 reads done
    epi_relu_store<4>(lds, 0, w * 64, lr, lg, acc);
  }
  __syncthreads();                                   // S5

  // ---- heads: alpha/beta = softplus(h2 @ [Wa|Wb] interleaved) + eps; v -> vbuf
  float regA0[2], regA1[2], regB0[2], regB1[2];      // deferred alpha/beta store
  const int j0 = 8 * w + 2 * lg;
  {
    bool jv = (j0 < K_DIM);
    float ba0 = jv ? ba[j0] : 0.f,     bb0 = jv ? bb[j0] : 0.f;
    float ba1 = jv ? ba[j0 + 1] : 0.f, bb1 = jv ? bb[j0 + 1] : 0.f;
    f32x4 acc[1][2];
    f32x4 binit = {ba0, bb0, ba1, bb1};
    acc[0][0] = binit; acc[0][1] = binit;
    gemm_direct<8, 64, 1>(lds, 0, Wpab, 16 * w, lr, lg, acc);

    float uu  = u[0] * 0.98f + 0.01f;
    float l2u = flog2(uu);
    float vv[2][2];
#pragma unroll
    for (int nr = 0; nr < 2; ++nr) {
      float a0  = sp_fast(acc[0][nr][0]) + 1e-4f;
      float b0v = sp_fast(acc[0][nr][1]) + 1e-4f;
      float a1  = sp_fast(acc[0][nr][2]) + 1e-4f;
      float b1v = sp_fast(acc[0][nr][3]) + 1e-4f;
      regA0[nr] = a0; regB0[nr] = b0v; regA1[nr] = a1; regB1[nr] = b1v;
      float t0 = fexp2(l2u * frcp(b0v));
      vv[nr][0] = fexp2(flog2(1.f - t0) * frcp(a0));
      float t1 = fexp2(l2u * frcp(b1v));
      vv[nr][1] = fexp2(flog2(1.f - t1) * frcp(a1));
    }
    __syncthreads();                                 // S6: all h2 reads done
    float* vbuf = reinterpret_cast<float*>(lds);     // fp32 stride-33 in tile
    if (jv) {
#pragma unroll
      for (int nr = 0; nr < 2; ++nr) {
        int row = 16 * nr + lr;
        if (j0 < K_DIM - 1)     vbuf[row * 33 + j0]     = vv[nr][0];
        if (j0 + 1 < K_DIM - 1) vbuf[row * 33 + j0 + 1] = vv[nr][1];
      }
    }
  }
  __syncthreads();                                   // S7: vbuf complete

  // ---- GEMM4 (scan fused): d = relu(Wd1^T pi^T + bd1), IN-PLACE over vbuf
  {
    bf16x8 pf[2];
    const float* vb = reinterpret_cast<const float*>(lds);
#pragma unroll
    for (int nr = 0; nr < 2; ++nr) {
      int row = 16 * nr + lr;
      const float* vrow = vb + row * 33;
      uint8_t* po = (w == 0) ? (lds + OFF_PI + row * 80) : nullptr;  // lg==0 path
      if      (lg == 0) pf[nr] = scan_frag<0>(vrow, po);
      else if (lg == 1) pf[nr] = scan_frag<1>(vrow, nullptr);
      else if (lg == 2) pf[nr] = scan_frag<2>(vrow, nullptr);
      else              pf[nr] = scan_frag<3>(vrow, nullptr);
    }
    f32x4 acc[4][2];
    acc_bias_init<4>(bd1, w * 64, lg, acc);
    bf16x8 w4[4];
    wload<256, 4>(Wpd1, 0, w * 64, lr, lg, w4);
#pragma unroll
    for (int mo = 0; mo < 4; ++mo)
#pragma unroll
      for (int nr = 0; nr < 2; ++nr)
        acc[mo][nr] = __builtin_amdgcn_mfma_f32_16x16x32_bf16(w4[mo], pf[nr], acc[mo][nr], 0, 0, 0);
    __syncthreads();                                 // S8: all vbuf reads done
    epi_relu_store<4>(lds, 0, w * 64, lr, lg, acc);
  }
  __syncthreads();                                   // S9

  // ---- GEMM5: recon = sigmoid(Wd2^T d^T + bd2); wave w: oc 48w.. (pad 192)
  {
    f32x4 acc[3][2];
#pragma unroll
    for (int mo = 0; mo < 3; ++mo) {
      int col0 = 48 * w + 16 * mo + 4 * lg;
      f32x4 t;
#pragma unroll
      for (int i = 0; i < 4; ++i) t[i] = (col0 + i < D_IN) ? bd2[col0 + i] : 0.f;
#pragma unroll
      for (int nr = 0; nr < 2; ++nr) acc[mo][nr] = t;
    }
    gemm_direct<8, 192, 3>(lds, 0, Wpd2, 48 * w, lr, lg, acc);
#pragma unroll
    for (int mo = 0; mo < 3; ++mo) {
      int col0 = 48 * w + 16 * mo + 4 * lg;
#pragma unroll
      for (int nr = 0; nr < 2; ++nr) {
        int row = 16 * nr + lr;
        float s0 = sigmoid_fast(acc[mo][nr][0]);
        float s1 = sigmoid_fast(acc[mo][nr][1]);
        float s2 = sigmoid_fast(acc[mo][nr][2]);
        float s3 = sigmoid_fast(acc[mo][nr][3]);
        float* dst = outRecon + (size_t)(r0 + row) * D_IN + col0;
        if (col0 < D_IN)     *reinterpret_cast<float2*>(dst)     = make_float2(s0, s1);
        if (col0 + 2 < D_IN) *reinterpret_cast<float2*>(dst + 2) = make_float2(s2, s3);
      }
    }
  }

  // ---- deferred global stores (no further barriers) ----
  if (j0 < K_DIM) {
#pragma unroll
    for (int nr = 0; nr < 2; ++nr) {
      int row = 16 * nr + lr;
      size_t base = (size_t)(r0 + row) * K_DIM + j0;
      *reinterpret_cast<float2*>(outAlpha + base) = make_float2(regA0[nr], regA1[nr]);
      *reinterpret_cast<float2*>(outBeta  + base) = make_float2(regB0[nr], regB1[nr]);
    }
  }
  {
    int row = tid >> 3, l8 = tid & 7;
#pragma unroll
    for (int half = 0; half < 2; ++half) {
      int f2 = l8 + half * 8;
      if (f2 < 15) {
        uint32_t pp = *reinterpret_cast<const uint32_t*>(lds + OFF_PI + row * 80 + f2 * 4);
        *reinterpret_cast<float2*>(outPi + (size_t)(r0 + row) * K_DIM + f2 * 2) =
            make_float2(unpk_lo(pp), unpk_hi(pp));
      }
    }
  }
}

extern "C" void kernel_launch(void* const* d_in, const int* in_sizes, int n_in,
                              void* d_out, int out_size, void* d_ws, size_t ws_size,
                              hipStream_t stream) {
  const float* Yh  = (const float*)d_in[0];
  const float* u   = (const float*)d_in[1];
  const float* W1  = (const float*)d_in[2];
  const float* b1  = (const float*)d_in[3];
  const float* W2  = (const float*)d_in[4];
  const float* b2  = (const float*)d_in[5];
  const float* Wa  = (const float*)d_in[6];
  const float* ba  = (const float*)d_in[7];
  const float* Wb  = (const float*)d_in[8];
  const float* bb  = (const float*)d_in[9];
  const float* Wd1 = (const float*)d_in[10];
  const float* bd1 = (const float*)d_in[11];
  const float* Wd2 = (const float*)d_in[12];
  const float* bd2 = (const float*)d_in[13];

  bf16_t* ws   = (bf16_t*)d_ws;
  bf16_t* Wp1  = ws;                  // 6*256*32 = 49152 elems
  bf16_t* Wp2  = Wp1 + 49152;         // 8*256*32 = 65536
  bf16_t* Wpab = Wp2 + 65536;         // 8*64*32  = 16384 (interleaved a/b)
  bf16_t* Wpd1 = Wpab + 16384;        // 1*256*32 = 8192
  bf16_t* Wpd2 = Wpd1 + 8192;         // 8*192*32 = 49152

  float* outRecon = (float*)d_out;
  float* outAlpha = outRecon + (size_t)N_ROWS * D_IN;
  float* outBeta  = outAlpha + (size_t)N_ROWS * K_DIM;
  float* outPi    = outBeta  + (size_t)N_ROWS * K_DIM;

  pack_b_kernel<<<192, 256, 0, stream>>>(W1, Wp1, 162, 256, 256, 6);
  pack_b_kernel<<<256, 256, 0, stream>>>(W2, Wp2, 256, 256, 256, 8);
  pack_ab_kernel<<<64, 256, 0, stream>>>(Wa, Wb, Wpab);
  pack_b_kernel<<<32, 256, 0, stream>>>(Wd1, Wpd1, 30, 256, 256, 1);
  pack_b_kernel<<<192, 256, 0, stream>>>(Wd2, Wpd2, 256, 162, 192, 8);

  usdn_fused<<<N_ROWS / ROWS, 256, 0, stream>>>(Yh, u, b1, b2, ba, bb, bd1, bd2,
                                                Wp1, Wp2, Wpab, Wpd1, Wpd2,
                                                outRecon, outAlpha, outBeta, outPi);
}

// Round 8
// 351.339 us; speedup vs baseline: 1.0795x; 1.0795x over previous
//
#include <hip/hip_runtime.h>
#include <hip/hip_bf16.h>

#define N_ROWS 262144
#define D_IN 162
#define K_DIM 30
#define ROWS 32          // rows per block
#define NTHR 128         // 2 waves per block: more independent blocks/CU

using bf16_t = __hip_bfloat16;
typedef __attribute__((ext_vector_type(8))) short bf16x8;
typedef __attribute__((ext_vector_type(4))) float f32x4;

// byte offset into the swizzled LDS tile: row stride 512 B, col in bf16 elems.
__device__ __forceinline__ int swz_byte(int row, int col) {
  int b = (row << 9) + (col << 1);
  return b ^ ((row & 7) << 4);
}

__device__ __forceinline__ uint32_t bf16b(float x) {
  return (uint32_t)__builtin_bit_cast(unsigned short, __float2bfloat16(x));
}
__device__ __forceinline__ uint32_t pack2(float lo, float hi) {
  return bf16b(lo) | (bf16b(hi) << 16);
}
__device__ __forceinline__ float unpk_lo(uint32_t p) {
  return __bfloat162float(__builtin_bit_cast(__hip_bfloat16, (unsigned short)(p & 0xffff)));
}
__device__ __forceinline__ float unpk_hi(uint32_t p) {
  return __bfloat162float(__builtin_bit_cast(__hip_bfloat16, (unsigned short)(p >> 16)));
}

__device__ __forceinline__ float fexp2(float x) { return __builtin_amdgcn_exp2f(x); }
__device__ __forceinline__ float flog2(float x) { return __builtin_amdgcn_logf(x); }
__device__ __forceinline__ float frcp (float x) { return __builtin_amdgcn_rcpf(x); }

__device__ __forceinline__ float sp_fast(float x) {        // softplus
  float e = fexp2(fabsf(x) * -1.44269504f);
  return fmaxf(x, 0.f) + 0.69314718f * flog2(1.f + e);
}
__device__ __forceinline__ float sigmoid_fast(float x) {
  return frcp(1.f + fexp2(x * -1.44269504f));
}

// ---------------- weight packing: fp32 [K][N] -> bf16 [kb][Np][32] ------------
__global__ void pack_b_kernel(const float* __restrict__ src, bf16_t* __restrict__ dst,
                              int K, int N, int Np, int KB) {
  int idx = blockIdx.x * 256 + threadIdx.x;
  int total = KB * Np * 32;
  if (idx >= total) return;
  int ks = idx & 31;
  int n  = (idx >> 5) % Np;
  int kb = idx / (32 * Np);
  int k  = kb * 32 + ks;
  float v = (k < K && n < N) ? src[k * N + n] : 0.f;
  dst[idx] = __float2bfloat16(v);
}

// Wa/Wb interleaved: out-col 2j = Wa[:,j], 2j+1 = Wb[:,j]
__global__ void pack_ab_kernel(const float* __restrict__ Wa, const float* __restrict__ Wb,
                               bf16_t* __restrict__ dst) {
  int idx = blockIdx.x * 256 + threadIdx.x;
  if (idx >= 8 * 64 * 32) return;
  int ks = idx & 31;
  int n  = (idx >> 5) & 63;
  int kb = idx >> 11;
  int k  = kb * 32 + ks;
  int j = n >> 1, s = n & 1;
  float v = (j < K_DIM) ? (s ? Wb[k * K_DIM + j] : Wa[k * K_DIM + j]) : 0.f;
  dst[idx] = __float2bfloat16(v);
}

// ---------------- weight fragment load (one kb, NMO out-col groups) -----------
template<int NP, int NMO>
__device__ __forceinline__ void wload(const bf16_t* __restrict__ Wp, int kb, int ocBase,
                                      int lr, int lg, bf16x8 (&out)[NMO]) {
#pragma unroll
  for (int mo = 0; mo < NMO; ++mo)
    out[mo] = *reinterpret_cast<const bf16x8*>(
        Wp + ((kb * NP + ocBase + 16 * mo + lr) << 5) + 8 * lg);
}

// ---------------- swapped-operand GEMM: read full tile into acc ---------------
template<int KB, int NP, int NMO>
__device__ __forceinline__ void gemm_direct(const uint8_t* lds, int srcOff,
                                            const bf16_t* __restrict__ Wp, int ocBase,
                                            int lr, int lg, f32x4 (&acc)[NMO][2]) {
  int bE[2], bO[2];   // even/odd-kb bases (128B pair-steps commute with row-XOR)
#pragma unroll
  for (int nr = 0; nr < 2; ++nr) {
    bE[nr] = srcOff + swz_byte(16 * nr + lr, 8 * lg);
    bO[nr] = srcOff + swz_byte(16 * nr + lr, 32 + 8 * lg);
  }
#pragma unroll
  for (int kb = 0; kb < KB; ++kb) {
    bf16x8 wf[NMO];
    wload<NP, NMO>(Wp, kb, ocBase, lr, lg, wf);
    bf16x8 hf[2];
#pragma unroll
    for (int nr = 0; nr < 2; ++nr) {
      int base = (kb & 1) ? bO[nr] : bE[nr];
      hf[nr] = *reinterpret_cast<const bf16x8*>(lds + base + (kb >> 1) * 128);
    }
#pragma unroll
    for (int mo = 0; mo < NMO; ++mo)
#pragma unroll
      for (int nr = 0; nr < 2; ++nr)
        acc[mo][nr] = __builtin_amdgcn_mfma_f32_16x16x32_bf16(wf[mo], hf[nr], acc[mo][nr], 0, 0, 0);
  }
}

template<int NMO>
__device__ __forceinline__ void acc_bias_init(const float* __restrict__ bias, int ocBase,
                                              int lg, f32x4 (&acc)[NMO][2]) {
#pragma unroll
  for (int mo = 0; mo < NMO; ++mo) {
    float4 bv = *reinterpret_cast<const float4*>(bias + ocBase + 16 * mo + 4 * lg);
    f32x4 t = {bv.x, bv.y, bv.z, bv.w};
#pragma unroll
    for (int nr = 0; nr < 2; ++nr) acc[mo][nr] = t;
  }
}

// relu -> packed bf16x4 -> one ds_write_b64 per fragment
template<int NMO>
__device__ __forceinline__ void epi_relu_store(uint8_t* lds, int dstOff, int ocBase,
                                               int lr, int lg, f32x4 (&acc)[NMO][2]) {
#pragma unroll
  for (int mo = 0; mo < NMO; ++mo)
#pragma unroll
    for (int nr = 0; nr < 2; ++nr) {
      int row = 16 * nr + lr;
      int col = ocBase + 16 * mo + 4 * lg;
      float x0 = fmaxf(acc[mo][nr][0], 0.f), x1 = fmaxf(acc[mo][nr][1], 0.f);
      float x2 = fmaxf(acc[mo][nr][2], 0.f), x3 = fmaxf(acc[mo][nr][3], 0.f);
      uint2 p; p.x = pack2(x0, x1); p.y = pack2(x2, x3);
      *reinterpret_cast<uint2*>(lds + dstOff + swz_byte(row, col)) = p;
    }
}

// ---------------- fused scan + fragment build ---------------------------------
template<int LG>
__device__ __forceinline__ bf16x8 scan_frag(const float* __restrict__ vrow,
                                            uint8_t* __restrict__ piPair) {
  float ex = 1.f, hold = 0.f;
  uint32_t pk0 = 0, pk1 = 0, pk2 = 0, pk3 = 0;
#pragma unroll
  for (int j = 0; j < 32; ++j) {
    float pi;
    if (j < K_DIM - 1)       { float vj = vrow[j]; pi = vj * ex; ex *= (1.f - vj); }
    else if (j == K_DIM - 1)   pi = ex;      // v_K forced to 1
    else                       pi = 0.f;     // pad K->32
    if (j & 1) {
      uint32_t p = pack2(hold, pi);
      if (piPair != nullptr && j < K_DIM)
        *reinterpret_cast<uint32_t*>(piPair + (j - 1) * 2) = p;
      if (j >= 8 * LG && j < 8 * LG + 8) {
        switch ((j - 8 * LG) >> 1) {
          case 0: pk0 = p; break; case 1: pk1 = p; break;
          case 2: pk2 = p; break; default: pk3 = p;
        }
      }
    } else hold = pi;
  }
  uint4 t = make_uint4(pk0, pk1, pk2, pk3);
  return __builtin_bit_cast(bf16x8, t);
}

// ---------------- fused forward ------------------------------------------------
// 2-wave blocks. LDS: one 16KB swizzled tile [0,16384) reused in-place:
// Yh -> h1 -> h2 -> vbuf -> d.  piT bf16 [32][40] at [16384,18944).
#define OFF_PI 16384

__launch_bounds__(NTHR, 4)
__global__ void usdn_fused(const float* __restrict__ Yh, const float* __restrict__ u,
                           const float* __restrict__ b1, const float* __restrict__ b2,
                           const float* __restrict__ ba, const float* __restrict__ bb,
                           const float* __restrict__ bd1, const float* __restrict__ bd2,
                           const bf16_t* __restrict__ Wp1, const bf16_t* __restrict__ Wp2,
                           const bf16_t* __restrict__ Wpab, const bf16_t* __restrict__ Wpd1,
                           const bf16_t* __restrict__ Wpd2,
                           float* __restrict__ outRecon, float* __restrict__ outAlpha,
                           float* __restrict__ outBeta, float* __restrict__ outPi) {
  __shared__ __align__(16) uint8_t lds[18944];

  const int tid = threadIdx.x;
  const int w  = tid >> 6;          // wave 0/1
  const int l  = tid & 63;
  const int lr = l & 15;
  const int lg = l >> 4;
  const int r0 = blockIdx.x * ROWS;

  // ---- stage Yh tile (32 x 162 fp32): 4 threads/row, 3 reg batches of 8
  {
    const int srow = tid >> 2, sl4 = tid & 3;
    const float2* src = reinterpret_cast<const float2*>(Yh + (size_t)(r0 + srow) * D_IN);
#pragma unroll
    for (int h = 0; h < 3; ++h) {
      float2 sv[8];
#pragma unroll
      for (int it = 0; it < 8; ++it) {
        int f2 = sl4 + (h * 8 + it) * 4;
        if (f2 < 81) sv[it] = src[f2];
      }
#pragma unroll
      for (int it = 0; it < 8; ++it) {
        int f2 = sl4 + (h * 8 + it) * 4;    // max 3+92=95: covers pad to col 191
        uint32_t p = 0;
        if (f2 < 81) p = pack2(sv[it].x, sv[it].y);
        *reinterpret_cast<uint32_t*>(lds + swz_byte(srow, f2 * 2)) = p;
      }
    }
  }
  __syncthreads();                                   // S1

  // ---- GEMM1: h1 = relu(W1^T x^T + b1), K=192, IN-PLACE. wave w: oc 128w..+127
  {
    f32x4 acc[8][2];
    acc_bias_init<8>(b1, w * 128, lg, acc);
    gemm_direct<6, 256, 8>(lds, 0, Wp1, w * 128, lr, lg, acc);
    __syncthreads();                                 // S2: all Yh reads done
    epi_relu_store<8>(lds, 0, w * 128, lr, lg, acc);
  }
  __syncthreads();                                   // S3

  // ---- GEMM2: h2 = relu(W2^T h1^T + b2), K=256, IN-PLACE
  {
    f32x4 acc[8][2];
    acc_bias_init<8>(b2, w * 128, lg, acc);
    gemm_direct<8, 256, 8>(lds, 0, Wp2, w * 128, lr, lg, acc);
    __syncthreads();                                 // S4: all h1 reads done
    epi_relu_store<8>(lds, 0, w * 128, lr, lg, acc);
  }
  __syncthreads();                                   // S5

  // ---- heads: wave w -> interleaved oc 32w..32w+31 (j = 16w+8mo+2lg, pairs)
  float regA[2][2][2], regB[2][2][2];   // [mo][nr][0/1]: deferred alpha/beta
  {
    f32x4 acc[2][2];
#pragma unroll
    for (int mo = 0; mo < 2; ++mo) {
      int j0 = 16 * w + 8 * mo + 2 * lg;
      bool jv = (j0 < K_DIM);
      float ba0 = jv ? ba[j0] : 0.f,     bb0 = jv ? bb[j0] : 0.f;
      float ba1 = jv ? ba[j0 + 1] : 0.f, bb1 = jv ? bb[j0 + 1] : 0.f;
      f32x4 binit = {ba0, bb0, ba1, bb1};
      acc[mo][0] = binit; acc[mo][1] = binit;
    }
    gemm_direct<8, 64, 2>(lds, 0, Wpab, 32 * w, lr, lg, acc);

    float uu  = u[0] * 0.98f + 0.01f;
    float l2u = flog2(uu);
    float vv[2][2][2];
#pragma unroll
    for (int mo = 0; mo < 2; ++mo)
#pragma unroll
      for (int nr = 0; nr < 2; ++nr) {
        float a0  = sp_fast(acc[mo][nr][0]) + 1e-4f;
        float b0v = sp_fast(acc[mo][nr][1]) + 1e-4f;
        float a1  = sp_fast(acc[mo][nr][2]) + 1e-4f;
        float b1v = sp_fast(acc[mo][nr][3]) + 1e-4f;
        regA[mo][nr][0] = a0; regB[mo][nr][0] = b0v;
        regA[mo][nr][1] = a1; regB[mo][nr][1] = b1v;
        float t0 = fexp2(l2u * frcp(b0v));
        vv[mo][nr][0] = fexp2(flog2(1.f - t0) * frcp(a0));
        float t1 = fexp2(l2u * frcp(b1v));
        vv[mo][nr][1] = fexp2(flog2(1.f - t1) * frcp(a1));
      }
    __syncthreads();                                 // S6: all h2 reads done
    float* vbuf = reinterpret_cast<float*>(lds);     // fp32 stride-33 in tile
#pragma unroll
    for (int mo = 0; mo < 2; ++mo) {
      int j0 = 16 * w + 8 * mo + 2 * lg;
      if (j0 < K_DIM) {
#pragma unroll
        for (int nr = 0; nr < 2; ++nr) {
          int row = 16 * nr + lr;
          if (j0 < K_DIM - 1)     vbuf[row * 33 + j0]     = vv[mo][nr][0];
          if (j0 + 1 < K_DIM - 1) vbuf[row * 33 + j0 + 1] = vv[mo][nr][1];
        }
      }
    }
  }
  __syncthreads();                                   // S7: vbuf complete

  // ---- GEMM4 (scan fused): d = relu(Wd1^T pi^T + bd1), IN-PLACE over vbuf
  {
    bf16x8 pf[2];
    const float* vb = reinterpret_cast<const float*>(lds);
#pragma unroll
    for (int nr = 0; nr < 2; ++nr) {
      int row = 16 * nr + lr;
      const float* vrow = vb + row * 33;
      uint8_t* po = (w == 0) ? (lds + OFF_PI + row * 80) : nullptr;  // lg==0 path
      if      (lg == 0) pf[nr] = scan_frag<0>(vrow, po);
      else if (lg == 1) pf[nr] = scan_frag<1>(vrow, nullptr);
      else if (lg == 2) pf[nr] = scan_frag<2>(vrow, nullptr);
      else              pf[nr] = scan_frag<3>(vrow, nullptr);
    }
    f32x4 acc[8][2];
    acc_bias_init<8>(bd1, w * 128, lg, acc);
    bf16x8 w4[8];
    wload<256, 8>(Wpd1, 0, w * 128, lr, lg, w4);
#pragma unroll
    for (int mo = 0; mo < 8; ++mo)
#pragma unroll
      for (int nr = 0; nr < 2; ++nr)
        acc[mo][nr] = __builtin_amdgcn_mfma_f32_16x16x32_bf16(w4[mo], pf[nr], acc[mo][nr], 0, 0, 0);
    __syncthreads();                                 // S8: all vbuf reads done
    epi_relu_store<8>(lds, 0, w * 128, lr, lg, acc);
  }
  __syncthreads();                                   // S9

  // ---- GEMM5: recon = sigmoid(Wd2^T d^T + bd2); wave w: oc 96w.. (pad 192)
  {
    f32x4 acc[6][2];
#pragma unroll
    for (int mo = 0; mo < 6; ++mo) {
      int col0 = 96 * w + 16 * mo + 4 * lg;
      f32x4 t;
#pragma unroll
      for (int i = 0; i < 4; ++i) t[i] = (col0 + i < D_IN) ? bd2[col0 + i] : 0.f;
#pragma unroll
      for (int nr = 0; nr < 2; ++nr) acc[mo][nr] = t;
    }
    gemm_direct<8, 192, 6>(lds, 0, Wpd2, 96 * w, lr, lg, acc);
#pragma unroll
    for (int mo = 0; mo < 6; ++mo) {
      int col0 = 96 * w + 16 * mo + 4 * lg;
#pragma unroll
      for (int nr = 0; nr < 2; ++nr) {
        int row = 16 * nr + lr;
        float s0 = sigmoid_fast(acc[mo][nr][0]);
        float s1 = sigmoid_fast(acc[mo][nr][1]);
        float s2 = sigmoid_fast(acc[mo][nr][2]);
        float s3 = sigmoid_fast(acc[mo][nr][3]);
        float* dst = outRecon + (size_t)(r0 + row) * D_IN + col0;
        if (col0 < D_IN)     *reinterpret_cast<float2*>(dst)     = make_float2(s0, s1);
        if (col0 + 2 < D_IN) *reinterpret_cast<float2*>(dst + 2) = make_float2(s2, s3);
      }
    }
  }

  // ---- deferred global stores (no further barriers) ----
#pragma unroll
  for (int mo = 0; mo < 2; ++mo) {
    int j0 = 16 * w + 8 * mo + 2 * lg;
    if (j0 < K_DIM) {
#pragma unroll
      for (int nr = 0; nr < 2; ++nr) {
        int row = 16 * nr + lr;
        size_t base = (size_t)(r0 + row) * K_DIM + j0;
        *reinterpret_cast<float2*>(outAlpha + base) =
            make_float2(regA[mo][nr][0], regA[mo][nr][1]);
        *reinterpret_cast<float2*>(outBeta  + base) =
            make_float2(regB[mo][nr][0], regB[mo][nr][1]);
      }
    }
  }
  {
    int row = tid >> 2, l4 = tid & 3;
#pragma unroll
    for (int it = 0; it < 4; ++it) {
      int f2 = l4 + it * 4;
      if (f2 < 15) {
        uint32_t pp = *reinterpret_cast<const uint32_t*>(lds + OFF_PI + row * 80 + f2 * 4);
        *reinterpret_cast<float2*>(outPi + (size_t)(r0 + row) * K_DIM + f2 * 2) =
            make_float2(unpk_lo(pp), unpk_hi(pp));
      }
    }
  }
}

extern "C" void kernel_launch(void* const* d_in, const int* in_sizes, int n_in,
                              void* d_out, int out_size, void* d_ws, size_t ws_size,
                              hipStream_t stream) {
  const float* Yh  = (const float*)d_in[0];
  const float* u   = (const float*)d_in[1];
  const float* W1  = (const float*)d_in[2];
  const float* b1  = (const float*)d_in[3];
  const float* W2  = (const float*)d_in[4];
  const float* b2  = (const float*)d_in[5];
  const float* Wa  = (const float*)d_in[6];
  const float* ba  = (const float*)d_in[7];
  const float* Wb  = (const float*)d_in[8];
  const float* bb  = (const float*)d_in[9];
  const float* Wd1 = (const float*)d_in[10];
  const float* bd1 = (const float*)d_in[11];
  const float* Wd2 = (const float*)d_in[12];
  const float* bd2 = (const float*)d_in[13];

  bf16_t* ws   = (bf16_t*)d_ws;
  bf16_t* Wp1  = ws;                  // 6*256*32 = 49152 elems
  bf16_t* Wp2  = Wp1 + 49152;         // 8*256*32 = 65536
  bf16_t* Wpab = Wp2 + 65536;         // 8*64*32  = 16384 (interleaved a/b)
  bf16_t* Wpd1 = Wpab + 16384;        // 1*256*32 = 8192
  bf16_t* Wpd2 = Wpd1 + 8192;         // 8*192*32 = 49152

  float* outRecon = (float*)d_out;
  float* outAlpha = outRecon + (size_t)N_ROWS * D_IN;
  float* outBeta  = outAlpha + (size_t)N_ROWS * K_DIM;
  float* outPi    = outBeta  + (size_t)N_ROWS * K_DIM;

  pack_b_kernel<<<192, 256, 0, stream>>>(W1, Wp1, 162, 256, 256, 6);
  pack_b_kernel<<<256, 256, 0, stream>>>(W2, Wp2, 256, 256, 256, 8);
  pack_ab_kernel<<<64, 256, 0, stream>>>(Wa, Wb, Wpab);
  pack_b_kernel<<<32, 256, 0, stream>>>(Wd1, Wpd1, 30, 256, 256, 1);
  pack_b_kernel<<<192, 256, 0, stream>>>(Wd2, Wpd2, 256, 162, 192, 8);

  usdn_fused<<<N_ROWS / ROWS, NTHR, 0, stream>>>(Yh, u, b1, b2, ba, bb, bd1, bd2,
                                                 Wp1, Wp2, Wpab, Wpd1, Wpd2,
                                                 outRecon, outAlpha, outBeta, outPi);
}

// Round 9
// 299.501 us; speedup vs baseline: 1.2663x; 1.1731x over previous
//
#include <hip/hip_runtime.h>
#include <hip/hip_bf16.h>

#define N_ROWS 262144
#define D_IN 162
#define K_DIM 30
#define ROWS 64          // rows per block (nr=4: 4 MFMAs per weight fragment)
#define NTHR 256

using bf16_t = __hip_bfloat16;
typedef __attribute__((ext_vector_type(8))) short bf16x8;
typedef __attribute__((ext_vector_type(4))) float f32x4;

// byte offset into the swizzled LDS tile: row stride 512 B, col in bf16 elems.
__device__ __forceinline__ int swz_byte(int row, int col) {
  int b = (row << 9) + (col << 1);
  return b ^ ((row & 7) << 4);
}

__device__ __forceinline__ uint32_t bf16b(float x) {
  return (uint32_t)__builtin_bit_cast(unsigned short, __float2bfloat16(x));
}
__device__ __forceinline__ uint32_t pack2(float lo, float hi) {
  return bf16b(lo) | (bf16b(hi) << 16);
}
__device__ __forceinline__ float unpk_lo(uint32_t p) {
  return __bfloat162float(__builtin_bit_cast(__hip_bfloat16, (unsigned short)(p & 0xffff)));
}
__device__ __forceinline__ float unpk_hi(uint32_t p) {
  return __bfloat162float(__builtin_bit_cast(__hip_bfloat16, (unsigned short)(p >> 16)));
}

__device__ __forceinline__ float fexp2(float x) { return __builtin_amdgcn_exp2f(x); }
__device__ __forceinline__ float flog2(float x) { return __builtin_amdgcn_logf(x); }
__device__ __forceinline__ float frcp (float x) { return __builtin_amdgcn_rcpf(x); }

__device__ __forceinline__ float sp_fast(float x) {        // softplus
  float e = fexp2(fabsf(x) * -1.44269504f);
  return fmaxf(x, 0.f) + 0.69314718f * flog2(1.f + e);
}
__device__ __forceinline__ float sigmoid_fast(float x) {
  return frcp(1.f + fexp2(x * -1.44269504f));
}

// ---------------- weight packing: fp32 [K][N] -> bf16 [kb][Np][32] ------------
__global__ void pack_b_kernel(const float* __restrict__ src, bf16_t* __restrict__ dst,
                              int K, int N, int Np, int KB) {
  int idx = blockIdx.x * 256 + threadIdx.x;
  int total = KB * Np * 32;
  if (idx >= total) return;
  int ks = idx & 31;
  int n  = (idx >> 5) % Np;
  int kb = idx / (32 * Np);
  int k  = kb * 32 + ks;
  float v = (k < K && n < N) ? src[k * N + n] : 0.f;
  dst[idx] = __float2bfloat16(v);
}

// Wa/Wb interleaved: out-col 2j = Wa[:,j], 2j+1 = Wb[:,j]
__global__ void pack_ab_kernel(const float* __restrict__ Wa, const float* __restrict__ Wb,
                               bf16_t* __restrict__ dst) {
  int idx = blockIdx.x * 256 + threadIdx.x;
  if (idx >= 8 * 64 * 32) return;
  int ks = idx & 31;
  int n  = (idx >> 5) & 63;
  int kb = idx >> 11;
  int k  = kb * 32 + ks;
  int j = n >> 1, s = n & 1;
  float v = (j < K_DIM) ? (s ? Wb[k * K_DIM + j] : Wa[k * K_DIM + j]) : 0.f;
  dst[idx] = __float2bfloat16(v);
}

// ---------------- weight fragment load (one kb, NMO out-col groups) -----------
template<int NP, int NMO>
__device__ __forceinline__ void wload(const bf16_t* __restrict__ Wp, int kb, int ocBase,
                                      int lr, int lg, bf16x8 (&out)[NMO]) {
#pragma unroll
  for (int mo = 0; mo < NMO; ++mo)
    out[mo] = *reinterpret_cast<const bf16x8*>(
        Wp + ((kb * NP + ocBase + 16 * mo + lr) << 5) + 8 * lg);
}

// ---------------- swapped-operand GEMM: read full tile into acc ---------------
// NR row-fragments per wave: each weight fragment feeds NR MFMAs.
template<int KB, int NP, int NMO, int NR>
__device__ __forceinline__ void gemm_direct(const uint8_t* lds, int srcOff,
                                            const bf16_t* __restrict__ Wp, int ocBase,
                                            int lr, int lg, f32x4 (&acc)[NMO][NR]) {
  int bE[NR], bO[NR];   // even/odd-kb bases (128B pair-steps commute with row-XOR)
#pragma unroll
  for (int nr = 0; nr < NR; ++nr) {
    bE[nr] = srcOff + swz_byte(16 * nr + lr, 8 * lg);
    bO[nr] = srcOff + swz_byte(16 * nr + lr, 32 + 8 * lg);
  }
#pragma unroll
  for (int kb = 0; kb < KB; ++kb) {
    bf16x8 wf[NMO];
    wload<NP, NMO>(Wp, kb, ocBase, lr, lg, wf);
    bf16x8 hf[NR];
#pragma unroll
    for (int nr = 0; nr < NR; ++nr) {
      int base = (kb & 1) ? bO[nr] : bE[nr];
      hf[nr] = *reinterpret_cast<const bf16x8*>(lds + base + (kb >> 1) * 128);
    }
#pragma unroll
    for (int mo = 0; mo < NMO; ++mo)
#pragma unroll
      for (int nr = 0; nr < NR; ++nr)
        acc[mo][nr] = __builtin_amdgcn_mfma_f32_16x16x32_bf16(wf[mo], hf[nr], acc[mo][nr], 0, 0, 0);
  }
}

template<int NMO, int NR>
__device__ __forceinline__ void acc_bias_init(const float* __restrict__ bias, int ocBase,
                                              int lg, f32x4 (&acc)[NMO][NR]) {
#pragma unroll
  for (int mo = 0; mo < NMO; ++mo) {
    float4 bv = *reinterpret_cast<const float4*>(bias + ocBase + 16 * mo + 4 * lg);
    f32x4 t = {bv.x, bv.y, bv.z, bv.w};
#pragma unroll
    for (int nr = 0; nr < NR; ++nr) acc[mo][nr] = t;
  }
}

// relu -> packed bf16x4 -> one ds_write_b64 per fragment
template<int NMO, int NR>
__device__ __forceinline__ void epi_relu_store(uint8_t* lds, int dstOff, int ocBase,
                                               int lr, int lg, f32x4 (&acc)[NMO][NR]) {
#pragma unroll
  for (int mo = 0; mo < NMO; ++mo)
#pragma unroll
    for (int nr = 0; nr < NR; ++nr) {
      int row = 16 * nr + lr;
      int col = ocBase + 16 * mo + 4 * lg;
      float x0 = fmaxf(acc[mo][nr][0], 0.f), x1 = fmaxf(acc[mo][nr][1], 0.f);
      float x2 = fmaxf(acc[mo][nr][2], 0.f), x3 = fmaxf(acc[mo][nr][3], 0.f);
      uint2 p; p.x = pack2(x0, x1); p.y = pack2(x2, x3);
      *reinterpret_cast<uint2*>(lds + dstOff + swz_byte(row, col)) = p;
    }
}

// ---------------- fused scan + fragment build ---------------------------------
template<int LG>
__device__ __forceinline__ bf16x8 scan_frag(const float* __restrict__ vrow,
                                            uint8_t* __restrict__ piPair) {
  float ex = 1.f, hold = 0.f;
  uint32_t pk0 = 0, pk1 = 0, pk2 = 0, pk3 = 0;
#pragma unroll
  for (int j = 0; j < 32; ++j) {
    float pi;
    if (j < K_DIM - 1)       { float vj = vrow[j]; pi = vj * ex; ex *= (1.f - vj); }
    else if (j == K_DIM - 1)   pi = ex;      // v_K forced to 1
    else                       pi = 0.f;     // pad K->32
    if (j & 1) {
      uint32_t p = pack2(hold, pi);
      if (piPair != nullptr && j < K_DIM)
        *reinterpret_cast<uint32_t*>(piPair + (j - 1) * 2) = p;
      if (j >= 8 * LG && j < 8 * LG + 8) {
        switch ((j - 8 * LG) >> 1) {
          case 0: pk0 = p; break; case 1: pk1 = p; break;
          case 2: pk2 = p; break; default: pk3 = p;
        }
      }
    } else hold = pi;
  }
  uint4 t = make_uint4(pk0, pk1, pk2, pk3);
  return __builtin_bit_cast(bf16x8, t);
}

// ---------------- fused forward ------------------------------------------------
// 64-row tile, 4 waves. LDS: one 32KB swizzled tile [0,32768) reused in-place:
// Yh -> h1 -> h2 -> vbuf(fp32[64][33], bytes [0,8448)) -> d.
// piT bf16 pairs [64 rows][80B] at [32768, 37888).
#define OFF_PI 32768

__launch_bounds__(NTHR, 4)
__global__ void usdn_fused(const float* __restrict__ Yh, const float* __restrict__ u,
                           const float* __restrict__ b1, const float* __restrict__ b2,
                           const float* __restrict__ ba, const float* __restrict__ bb,
                           const float* __restrict__ bd1, const float* __restrict__ bd2,
                           const bf16_t* __restrict__ Wp1, const bf16_t* __restrict__ Wp2,
                           const bf16_t* __restrict__ Wpab, const bf16_t* __restrict__ Wpd1,
                           const bf16_t* __restrict__ Wpd2,
                           float* __restrict__ outRecon, float* __restrict__ outAlpha,
                           float* __restrict__ outBeta, float* __restrict__ outPi) {
  __shared__ __align__(16) uint8_t lds[37888];

  const int tid = threadIdx.x;
  const int w  = tid >> 6;
  const int l  = tid & 63;
  const int lr = l & 15;
  const int lg = l >> 4;
  const int r0 = blockIdx.x * ROWS;

  // ---- stage Yh tile (64 x 162 fp32): 4 threads/row, 3 reg batches of 8 float2
  {
    const int srow = tid >> 2, sl4 = tid & 3;
    const float2* src = reinterpret_cast<const float2*>(Yh + (size_t)(r0 + srow) * D_IN);
#pragma unroll
    for (int h = 0; h < 3; ++h) {
      float2 sv[8];
#pragma unroll
      for (int it = 0; it < 8; ++it) {
        int f2 = sl4 + (h * 8 + it) * 4;
        if (f2 < 81) sv[it] = src[f2];
      }
#pragma unroll
      for (int it = 0; it < 8; ++it) {
        int f2 = sl4 + (h * 8 + it) * 4;    // covers 0..95: data + pad to col 191
        uint32_t p = 0;
        if (f2 < 81) p = pack2(sv[it].x, sv[it].y);
        *reinterpret_cast<uint32_t*>(lds + swz_byte(srow, f2 * 2)) = p;
      }
    }
  }
  __syncthreads();                                   // S1

  // ---- GEMM1: h1 = relu(W1^T x^T + b1), K=192, IN-PLACE. wave w: oc 64w..+63
  {
    f32x4 acc[4][4];
    acc_bias_init<4, 4>(b1, w * 64, lg, acc);
    gemm_direct<6, 256, 4, 4>(lds, 0, Wp1, w * 64, lr, lg, acc);
    __syncthreads();                                 // S2: all Yh reads done
    epi_relu_store<4, 4>(lds, 0, w * 64, lr, lg, acc);
  }
  __syncthreads();                                   // S3

  // ---- GEMM2: h2 = relu(W2^T h1^T + b2), K=256, IN-PLACE
  {
    f32x4 acc[4][4];
    acc_bias_init<4, 4>(b2, w * 64, lg, acc);
    gemm_direct<8, 256, 4, 4>(lds, 0, Wp2, w * 64, lr, lg, acc);
    __syncthreads();                                 // S4: all h1 reads done
    epi_relu_store<4, 4>(lds, 0, w * 64, lr, lg, acc);
  }
  __syncthreads();                                   // S5

  // ---- heads: wave w -> interleaved oc 16w..16w+15 (j0 = 8w+2lg), 4 row-frags
  float regA[4][2], regB[4][2];                      // [nr][0/1] deferred
  const int j0 = 8 * w + 2 * lg;
  {
    bool jv = (j0 < K_DIM);
    float ba0 = jv ? ba[j0] : 0.f,     bb0 = jv ? bb[j0] : 0.f;
    float ba1 = jv ? ba[j0 + 1] : 0.f, bb1 = jv ? bb[j0 + 1] : 0.f;
    f32x4 acc[1][4];
    f32x4 binit = {ba0, bb0, ba1, bb1};
#pragma unroll
    for (int nr = 0; nr < 4; ++nr) acc[0][nr] = binit;
    gemm_direct<8, 64, 1, 4>(lds, 0, Wpab, 16 * w, lr, lg, acc);

    float uu  = u[0] * 0.98f + 0.01f;
    float l2u = flog2(uu);
    float vv[4][2];
#pragma unroll
    for (int nr = 0; nr < 4; ++nr) {
      float a0  = sp_fast(acc[0][nr][0]) + 1e-4f;
      float b0v = sp_fast(acc[0][nr][1]) + 1e-4f;
      float a1  = sp_fast(acc[0][nr][2]) + 1e-4f;
      float b1v = sp_fast(acc[0][nr][3]) + 1e-4f;
      regA[nr][0] = a0; regB[nr][0] = b0v;
      regA[nr][1] = a1; regB[nr][1] = b1v;
      float t0 = fexp2(l2u * frcp(b0v));
      vv[nr][0] = fexp2(flog2(1.f - t0) * frcp(a0));
      float t1 = fexp2(l2u * frcp(b1v));
      vv[nr][1] = fexp2(flog2(1.f - t1) * frcp(a1));
    }
    __syncthreads();                                 // S6: all h2 reads done
    float* vbuf = reinterpret_cast<float*>(lds);     // fp32 [64][33] in tile
    if (jv) {
#pragma unroll
      for (int nr = 0; nr < 4; ++nr) {
        int row = 16 * nr + lr;
        if (j0 < K_DIM - 1)     vbuf[row * 33 + j0]     = vv[nr][0];
        if (j0 + 1 < K_DIM - 1) vbuf[row * 33 + j0 + 1] = vv[nr][1];
      }
    }
  }
  __syncthreads();                                   // S7: vbuf complete

  // ---- GEMM4 (scan fused): d = relu(Wd1^T pi^T + bd1), IN-PLACE over vbuf
  {
    bf16x8 pf[4];
    const float* vb = reinterpret_cast<const float*>(lds);
#pragma unroll
    for (int nr = 0; nr < 4; ++nr) {
      int row = 16 * nr + lr;
      const float* vrow = vb + row * 33;
      uint8_t* po = (w == 0) ? (lds + OFF_PI + row * 80) : nullptr;  // lg==0 path
      if      (lg == 0) pf[nr] = scan_frag<0>(vrow, po);
      else if (lg == 1) pf[nr] = scan_frag<1>(vrow, nullptr);
      else if (lg == 2) pf[nr] = scan_frag<2>(vrow, nullptr);
      else              pf[nr] = scan_frag<3>(vrow, nullptr);
    }
    f32x4 acc[4][4];
    acc_bias_init<4, 4>(bd1, w * 64, lg, acc);
    bf16x8 w4[4];
    wload<256, 4>(Wpd1, 0, w * 64, lr, lg, w4);
#pragma unroll
    for (int mo = 0; mo < 4; ++mo)
#pragma unroll
      for (int nr = 0; nr < 4; ++nr)
        acc[mo][nr] = __builtin_amdgcn_mfma_f32_16x16x32_bf16(w4[mo], pf[nr], acc[mo][nr], 0, 0, 0);
    __syncthreads();                                 // S8: all vbuf reads done
    epi_relu_store<4, 4>(lds, 0, w * 64, lr, lg, acc);
  }
  __syncthreads();                                   // S9

  // ---- GEMM5: recon = sigmoid(Wd2^T d^T + bd2); wave w: oc 48w.. (pad 192)
  {
    f32x4 acc[3][4];
#pragma unroll
    for (int mo = 0; mo < 3; ++mo) {
      int col0 = 48 * w + 16 * mo + 4 * lg;
      f32x4 t;
#pragma unroll
      for (int i = 0; i < 4; ++i) t[i] = (col0 + i < D_IN) ? bd2[col0 + i] : 0.f;
#pragma unroll
      for (int nr = 0; nr < 4; ++nr) acc[mo][nr] = t;
    }
    gemm_direct<8, 192, 3, 4>(lds, 0, Wpd2, 48 * w, lr, lg, acc);
#pragma unroll
    for (int mo = 0; mo < 3; ++mo) {
      int col0 = 48 * w + 16 * mo + 4 * lg;
#pragma unroll
      for (int nr = 0; nr < 4; ++nr) {
        int row = 16 * nr + lr;
        float s0 = sigmoid_fast(acc[mo][nr][0]);
        float s1 = sigmoid_fast(acc[mo][nr][1]);
        float s2 = sigmoid_fast(acc[mo][nr][2]);
        float s3 = sigmoid_fast(acc[mo][nr][3]);
        float* dst = outRecon + (size_t)(r0 + row) * D_IN + col0;
        if (col0 < D_IN)     *reinterpret_cast<float2*>(dst)     = make_float2(s0, s1);
        if (col0 + 2 < D_IN) *reinterpret_cast<float2*>(dst + 2) = make_float2(s2, s3);
      }
    }
  }

  // ---- deferred global stores (no further barriers) ----
  if (j0 < K_DIM) {
#pragma unroll
    for (int nr = 0; nr < 4; ++nr) {
      int row = 16 * nr + lr;
      size_t base = (size_t)(r0 + row) * K_DIM + j0;
      *reinterpret_cast<float2*>(outAlpha + base) = make_float2(regA[nr][0], regA[nr][1]);
      *reinterpret_cast<float2*>(outBeta  + base) = make_float2(regB[nr][0], regB[nr][1]);
    }
  }
  {
    int row = tid >> 2, l4 = tid & 3;
#pragma unroll
    for (int it = 0; it < 4; ++it) {
      int f2 = l4 + it * 4;
      if (f2 < 15) {
        uint32_t pp = *reinterpret_cast<const uint32_t*>(lds + OFF_PI + row * 80 + f2 * 4);
        *reinterpret_cast<float2*>(outPi + (size_t)(r0 + row) * K_DIM + f2 * 2) =
            make_float2(unpk_lo(pp), unpk_hi(pp));
      }
    }
  }
}

extern "C" void kernel_launch(void* const* d_in, const int* in_sizes, int n_in,
                              void* d_out, int out_size, void* d_ws, size_t ws_size,
                              hipStream_t stream) {
  const float* Yh  = (const float*)d_in[0];
  const float* u   = (const float*)d_in[1];
  const float* W1  = (const float*)d_in[2];
  const float* b1  = (const float*)d_in[3];
  const float* W2  = (const float*)d_in[4];
  const float* b2  = (const float*)d_in[5];
  const float* Wa  = (const float*)d_in[6];
  const float* ba  = (const float*)d_in[7];
  const float* Wb  = (const float*)d_in[8];
  const float* bb  = (const float*)d_in[9];
  const float* Wd1 = (const float*)d_in[10];
  const float* bd1 = (const float*)d_in[11];
  const float* Wd2 = (const float*)d_in[12];
  const float* bd2 = (const float*)d_in[13];

  bf16_t* ws   = (bf16_t*)d_ws;
  bf16_t* Wp1  = ws;                  // 6*256*32 = 49152 elems
  bf16_t* Wp2  = Wp1 + 49152;         // 8*256*32 = 65536
  bf16_t* Wpab = Wp2 + 65536;         // 8*64*32  = 16384 (interleaved a/b)
  bf16_t* Wpd1 = Wpab + 16384;        // 1*256*32 = 8192
  bf16_t* Wpd2 = Wpd1 + 8192;         // 8*192*32 = 49152

  float* outRecon = (float*)d_out;
  float* outAlpha = outRecon + (size_t)N_ROWS * D_IN;
  float* outBeta  = outAlpha + (size_t)N_ROWS * K_DIM;
  float* outPi    = outBeta  + (size_t)N_ROWS * K_DIM;

  pack_b_kernel<<<192, 256, 0, stream>>>(W1, Wp1, 162, 256, 256, 6);
  pack_b_kernel<<<256, 256, 0, stream>>>(W2, Wp2, 256, 256, 256, 8);
  pack_ab_kernel<<<64, 256, 0, stream>>>(Wa, Wb, Wpab);
  pack_b_kernel<<<32, 256, 0, stream>>>(Wd1, Wpd1, 30, 256, 256, 1);
  pack_b_kernel<<<192, 256, 0, stream>>>(Wd2, Wpd2, 256, 162, 192, 8);

  usdn_fused<<<N_ROWS / ROWS, NTHR, 0, stream>>>(Yh, u, b1, b2, ba, bb, bd1, bd2,
                                                 Wp1, Wp2, Wpab, Wpd1, Wpd2,
                                                 outRecon, outAlpha, outBeta, outPi);
}

// Round 10
// 278.751 us; speedup vs baseline: 1.3606x; 1.0744x over previous
//
#include <hip/hip_runtime.h>
#include <hip/hip_bf16.h>

#define N_ROWS 262144
#define D_IN 162
#define K_DIM 30
#define ROWS 32          // rows per block
#define NTHR 512         // 8 waves x 32 out-cols: total regs <=64 -> 32 waves/CU

using bf16_t = __hip_bfloat16;
typedef __attribute__((ext_vector_type(8))) short bf16x8;
typedef __attribute__((ext_vector_type(4))) float f32x4;

// byte offset into a swizzled LDS tile: row stride 512 B, col in bf16 elems.
__device__ __forceinline__ int swz_byte(int row, int col) {
  int b = (row << 9) + (col << 1);
  return b ^ ((row & 7) << 4);
}

__device__ __forceinline__ uint32_t bf16b(float x) {
  return (uint32_t)__builtin_bit_cast(unsigned short, __float2bfloat16(x));
}
__device__ __forceinline__ uint32_t pack2(float lo, float hi) {
  return bf16b(lo) | (bf16b(hi) << 16);
}
__device__ __forceinline__ float unpk_lo(uint32_t p) {
  return __bfloat162float(__builtin_bit_cast(__hip_bfloat16, (unsigned short)(p & 0xffff)));
}
__device__ __forceinline__ float unpk_hi(uint32_t p) {
  return __bfloat162float(__builtin_bit_cast(__hip_bfloat16, (unsigned short)(p >> 16)));
}

__device__ __forceinline__ float fexp2(float x) { return __builtin_amdgcn_exp2f(x); }
__device__ __forceinline__ float flog2(float x) { return __builtin_amdgcn_logf(x); }
__device__ __forceinline__ float frcp (float x) { return __builtin_amdgcn_rcpf(x); }

__device__ __forceinline__ float sp_fast(float x) {        // softplus
  float e = fexp2(fabsf(x) * -1.44269504f);
  return fmaxf(x, 0.f) + 0.69314718f * flog2(1.f + e);
}
__device__ __forceinline__ float sigmoid_fast(float x) {
  return frcp(1.f + fexp2(x * -1.44269504f));
}

// ---------------- weight packing: fp32 [K][N] -> bf16 [kb][Np][32] ------------
__global__ void pack_b_kernel(const float* __restrict__ src, bf16_t* __restrict__ dst,
                              int K, int N, int Np, int KB) {
  int idx = blockIdx.x * 256 + threadIdx.x;
  int total = KB * Np * 32;
  if (idx >= total) return;
  int ks = idx & 31;
  int n  = (idx >> 5) % Np;
  int kb = idx / (32 * Np);
  int k  = kb * 32 + ks;
  float v = (k < K && n < N) ? src[k * N + n] : 0.f;
  dst[idx] = __float2bfloat16(v);
}

// Wa/Wb interleaved: out-col 2j = Wa[:,j], 2j+1 = Wb[:,j]
__global__ void pack_ab_kernel(const float* __restrict__ Wa, const float* __restrict__ Wb,
                               bf16_t* __restrict__ dst) {
  int idx = blockIdx.x * 256 + threadIdx.x;
  if (idx >= 8 * 64 * 32) return;
  int ks = idx & 31;
  int n  = (idx >> 5) & 63;
  int kb = idx >> 11;
  int k  = kb * 32 + ks;
  int j = n >> 1, s = n & 1;
  float v = (j < K_DIM) ? (s ? Wb[k * K_DIM + j] : Wa[k * K_DIM + j]) : 0.f;
  dst[idx] = __float2bfloat16(v);
}

// ---------------- weight fragment load (one kb, NMO out-col groups) -----------
template<int NP, int NMO>
__device__ __forceinline__ void wload(const bf16_t* __restrict__ Wp, int kb, int ocBase,
                                      int lr, int lg, bf16x8 (&out)[NMO]) {
#pragma unroll
  for (int mo = 0; mo < NMO; ++mo)
    out[mo] = *reinterpret_cast<const bf16x8*>(
        Wp + ((kb * NP + ocBase + 16 * mo + lr) << 5) + 8 * lg);
}

// ---------------- swapped-operand GEMM ----------------------------------------
template<int KB, int NP, int NMO, int NR>
__device__ __forceinline__ void gemm_direct(const uint8_t* lds, int srcOff,
                                            const bf16_t* __restrict__ Wp, int ocBase,
                                            int lr, int lg, f32x4 (&acc)[NMO][NR]) {
  int bE[NR], bO[NR];   // even/odd-kb bases (128B pair-steps commute with row-XOR)
#pragma unroll
  for (int nr = 0; nr < NR; ++nr) {
    bE[nr] = srcOff + swz_byte(16 * nr + lr, 8 * lg);
    bO[nr] = srcOff + swz_byte(16 * nr + lr, 32 + 8 * lg);
  }
#pragma unroll
  for (int kb = 0; kb < KB; ++kb) {
    bf16x8 wf[NMO];
    wload<NP, NMO>(Wp, kb, ocBase, lr, lg, wf);
    bf16x8 hf[NR];
#pragma unroll
    for (int nr = 0; nr < NR; ++nr) {
      int base = (kb & 1) ? bO[nr] : bE[nr];
      hf[nr] = *reinterpret_cast<const bf16x8*>(lds + base + (kb >> 1) * 128);
    }
#pragma unroll
    for (int mo = 0; mo < NMO; ++mo)
#pragma unroll
      for (int nr = 0; nr < NR; ++nr)
        acc[mo][nr] = __builtin_amdgcn_mfma_f32_16x16x32_bf16(wf[mo], hf[nr], acc[mo][nr], 0, 0, 0);
  }
}

template<int NMO, int NR>
__device__ __forceinline__ void acc_bias_init(const float* __restrict__ bias, int ocBase,
                                              int lg, f32x4 (&acc)[NMO][NR]) {
#pragma unroll
  for (int mo = 0; mo < NMO; ++mo) {
    float4 bv = *reinterpret_cast<const float4*>(bias + ocBase + 16 * mo + 4 * lg);
    f32x4 t = {bv.x, bv.y, bv.z, bv.w};
#pragma unroll
    for (int nr = 0; nr < NR; ++nr) acc[mo][nr] = t;
  }
}

// relu -> packed bf16x4 -> one ds_write_b64 per fragment
template<int NMO, int NR>
__device__ __forceinline__ void epi_relu_store(uint8_t* lds, int dstOff, int ocBase,
                                               int lr, int lg, f32x4 (&acc)[NMO][NR]) {
#pragma unroll
  for (int mo = 0; mo < NMO; ++mo)
#pragma unroll
    for (int nr = 0; nr < NR; ++nr) {
      int row = 16 * nr + lr;
      int col = ocBase + 16 * mo + 4 * lg;
      float x0 = fmaxf(acc[mo][nr][0], 0.f), x1 = fmaxf(acc[mo][nr][1], 0.f);
      float x2 = fmaxf(acc[mo][nr][2], 0.f), x3 = fmaxf(acc[mo][nr][3], 0.f);
      uint2 p; p.x = pack2(x0, x1); p.y = pack2(x2, x3);
      *reinterpret_cast<uint2*>(lds + dstOff + swz_byte(row, col)) = p;
    }
}

// ---------------- fused scan + fragment build ---------------------------------
template<int LG>
__device__ __forceinline__ bf16x8 scan_frag(const float* __restrict__ vrow,
                                            uint8_t* __restrict__ piPair) {
  float ex = 1.f, hold = 0.f;
  uint32_t pk0 = 0, pk1 = 0, pk2 = 0, pk3 = 0;
#pragma unroll
  for (int j = 0; j < 32; ++j) {
    float pi;
    if (j < K_DIM - 1)       { float vj = vrow[j]; pi = vj * ex; ex *= (1.f - vj); }
    else if (j == K_DIM - 1)   pi = ex;      // v_K forced to 1
    else                       pi = 0.f;     // pad K->32
    if (j & 1) {
      uint32_t p = pack2(hold, pi);
      if (piPair != nullptr && j < K_DIM)
        *reinterpret_cast<uint32_t*>(piPair + (j - 1) * 2) = p;
      if (j >= 8 * LG && j < 8 * LG + 8) {
        switch ((j - 8 * LG) >> 1) {
          case 0: pk0 = p; break; case 1: pk1 = p; break;
          case 2: pk2 = p; break; default: pk3 = p;
        }
      }
    } else hold = pi;
  }
  uint4 t = make_uint4(pk0, pk1, pk2, pk3);
  return __builtin_bit_cast(bf16x8, t);
}

// ---------------- fused forward ------------------------------------------------
// 8-wave 512-thr blocks, 32-row tile, wave w owns 32 out-cols (mo=2, nr=2).
// LDS ping-pong: A=[0,16K): Yh -> h2 -> d ; B=[16K,32K): h1 -> vbuf fp32[32][33];
// piT bf16 pairs [32 rows][80B] at [32768, 35328).  5 barriers total.
#define OFF_B  16384
#define OFF_PI 32768

__launch_bounds__(NTHR, 8)
__global__ void usdn_fused(const float* __restrict__ Yh, const float* __restrict__ u,
                           const float* __restrict__ b1, const float* __restrict__ b2,
                           const float* __restrict__ ba, const float* __restrict__ bb,
                           const float* __restrict__ bd1, const float* __restrict__ bd2,
                           const bf16_t* __restrict__ Wp1, const bf16_t* __restrict__ Wp2,
                           const bf16_t* __restrict__ Wpab, const bf16_t* __restrict__ Wpd1,
                           const bf16_t* __restrict__ Wpd2,
                           float* __restrict__ outRecon, float* __restrict__ outAlpha,
                           float* __restrict__ outBeta, float* __restrict__ outPi) {
  __shared__ __align__(16) uint8_t lds[35328];

  const int tid = threadIdx.x;
  const int w  = tid >> 6;          // 0..7
  const int l  = tid & 63;
  const int lr = l & 15;
  const int lg = l >> 4;
  const int r0 = blockIdx.x * ROWS;

  // ---- stage Yh tile (32 x 162 fp32): 16 threads/row, 2 reg batches of 3
  {
    const int srow = tid >> 4, s16 = tid & 15;
    const float2* src = reinterpret_cast<const float2*>(Yh + (size_t)(r0 + srow) * D_IN);
#pragma unroll
    for (int h = 0; h < 2; ++h) {
      float2 sv[3];
#pragma unroll
      for (int it = 0; it < 3; ++it) {
        int f2 = s16 + (h * 3 + it) * 16;
        if (f2 < 81) sv[it] = src[f2];
      }
#pragma unroll
      for (int it = 0; it < 3; ++it) {
        int f2 = s16 + (h * 3 + it) * 16;   // 0..95: data + zero pad to col 191
        uint32_t p = 0;
        if (f2 < 81) p = pack2(sv[it].x, sv[it].y);
        *reinterpret_cast<uint32_t*>(lds + swz_byte(srow, f2 * 2)) = p;
      }
    }
  }
  __syncthreads();                                   // S1

  // ---- GEMM1: h1 = relu(W1^T x^T + b1), K=192, A -> B. wave w: oc 32w..32w+31
  {
    f32x4 acc[2][2];
    acc_bias_init<2, 2>(b1, w * 32, lg, acc);
    gemm_direct<6, 256, 2, 2>(lds, 0, Wp1, w * 32, lr, lg, acc);
    epi_relu_store<2, 2>(lds, OFF_B, w * 32, lr, lg, acc);
  }
  __syncthreads();                                   // S2

  // ---- GEMM2: h2 = relu(W2^T h1^T + b2), K=256, B -> A (Yh dead after S2)
  {
    f32x4 acc[2][2];
    acc_bias_init<2, 2>(b2, w * 32, lg, acc);
    gemm_direct<8, 256, 2, 2>(lds, OFF_B, Wp2, w * 32, lr, lg, acc);
    epi_relu_store<2, 2>(lds, 0, w * 32, lr, lg, acc);
  }
  __syncthreads();                                   // S3

  // ---- heads (waves 0..3): alpha/beta from A(h2); v -> vbuf in B (h1 dead)
  float regA[2][2], regB[2][2];                      // [nr][0/1], valid w<4
  const int j0 = 8 * w + 2 * lg;
  if (w < 4) {
    bool jv = (j0 < K_DIM);
    float ba0 = jv ? ba[j0] : 0.f,     bb0 = jv ? bb[j0] : 0.f;
    float ba1 = jv ? ba[j0 + 1] : 0.f, bb1 = jv ? bb[j0 + 1] : 0.f;
    f32x4 acc[1][2];
    f32x4 binit = {ba0, bb0, ba1, bb1};
    acc[0][0] = binit; acc[0][1] = binit;
    gemm_direct<8, 64, 1, 2>(lds, 0, Wpab, 16 * w, lr, lg, acc);

    float uu  = u[0] * 0.98f + 0.01f;
    float l2u = flog2(uu);
    float* vbuf = reinterpret_cast<float*>(lds + OFF_B);   // fp32 [32][33]
#pragma unroll
    for (int nr = 0; nr < 2; ++nr) {
      int row = 16 * nr + lr;
      float a0  = sp_fast(acc[0][nr][0]) + 1e-4f;
      float b0v = sp_fast(acc[0][nr][1]) + 1e-4f;
      float a1  = sp_fast(acc[0][nr][2]) + 1e-4f;
      float b1v = sp_fast(acc[0][nr][3]) + 1e-4f;
      regA[nr][0] = a0; regB[nr][0] = b0v;
      regA[nr][1] = a1; regB[nr][1] = b1v;
      if (jv) {
        if (j0 < K_DIM - 1) {
          float t = fexp2(l2u * frcp(b0v));
          vbuf[row * 33 + j0] = fexp2(flog2(1.f - t) * frcp(a0));
        }
        if (j0 + 1 < K_DIM - 1) {
          float t = fexp2(l2u * frcp(b1v));
          vbuf[row * 33 + j0 + 1] = fexp2(flog2(1.f - t) * frcp(a1));
        }
      }
    }
  }
  __syncthreads();                                   // S4: vbuf complete

  // ---- GEMM4 (scan fused): d = relu(Wd1^T pi^T + bd1) -> A (h2 dead)
  {
    bf16x8 pf[2];
    const float* vb = reinterpret_cast<const float*>(lds + OFF_B);
#pragma unroll
    for (int nr = 0; nr < 2; ++nr) {
      int row = 16 * nr + lr;
      const float* vrow = vb + row * 33;
      uint8_t* po = (w == 0) ? (lds + OFF_PI + row * 80) : nullptr;  // lg==0 path
      if      (lg == 0) pf[nr] = scan_frag<0>(vrow, po);
      else if (lg == 1) pf[nr] = scan_frag<1>(vrow, nullptr);
      else if (lg == 2) pf[nr] = scan_frag<2>(vrow, nullptr);
      else              pf[nr] = scan_frag<3>(vrow, nullptr);
    }
    f32x4 acc[2][2];
    acc_bias_init<2, 2>(bd1, w * 32, lg, acc);
    bf16x8 w4[2];
    wload<256, 2>(Wpd1, 0, w * 32, lr, lg, w4);
#pragma unroll
    for (int mo = 0; mo < 2; ++mo)
#pragma unroll
      for (int nr = 0; nr < 2; ++nr)
        acc[mo][nr] = __builtin_amdgcn_mfma_f32_16x16x32_bf16(w4[mo], pf[nr], acc[mo][nr], 0, 0, 0);
    epi_relu_store<2, 2>(lds, 0, w * 32, lr, lg, acc);
  }
  __syncthreads();                                   // S5

  // ---- GEMM5 (waves 0..5): recon = sigmoid(Wd2^T d^T + bd2); oc 32w.. (pad 192)
  if (w < 6) {
    f32x4 acc[2][2];
#pragma unroll
    for (int mo = 0; mo < 2; ++mo) {
      int col0 = 32 * w + 16 * mo + 4 * lg;
      f32x4 t;
#pragma unroll
      for (int i = 0; i < 4; ++i) t[i] = (col0 + i < D_IN) ? bd2[col0 + i] : 0.f;
#pragma unroll
      for (int nr = 0; nr < 2; ++nr) acc[mo][nr] = t;
    }
    gemm_direct<8, 192, 2, 2>(lds, 0, Wpd2, 32 * w, lr, lg, acc);
#pragma unroll
    for (int mo = 0; mo < 2; ++mo) {
      int col0 = 32 * w + 16 * mo + 4 * lg;
#pragma unroll
      for (int nr = 0; nr < 2; ++nr) {
        int row = 16 * nr + lr;
        float s0 = sigmoid_fast(acc[mo][nr][0]);
        float s1 = sigmoid_fast(acc[mo][nr][1]);
        float s2 = sigmoid_fast(acc[mo][nr][2]);
        float s3 = sigmoid_fast(acc[mo][nr][3]);
        float* dst = outRecon + (size_t)(r0 + row) * D_IN + col0;
        if (col0 < D_IN)     *reinterpret_cast<float2*>(dst)     = make_float2(s0, s1);
        if (col0 + 2 < D_IN) *reinterpret_cast<float2*>(dst + 2) = make_float2(s2, s3);
      }
    }
  }

  // ---- deferred global stores (no further barriers) ----
  if (w < 4 && j0 < K_DIM) {
#pragma unroll
    for (int nr = 0; nr < 2; ++nr) {
      int row = 16 * nr + lr;
      size_t base = (size_t)(r0 + row) * K_DIM + j0;
      *reinterpret_cast<float2*>(outAlpha + base) = make_float2(regA[nr][0], regA[nr][1]);
      *reinterpret_cast<float2*>(outBeta  + base) = make_float2(regB[nr][0], regB[nr][1]);
    }
  }
  if (tid < 128) {
    int row = tid >> 2, l4 = tid & 3;
#pragma unroll
    for (int it = 0; it < 4; ++it) {
      int f2 = l4 + it * 4;
      if (f2 < 15) {
        uint32_t pp = *reinterpret_cast<const uint32_t*>(lds + OFF_PI + row * 80 + f2 * 4);
        *reinterpret_cast<float2*>(outPi + (size_t)(r0 + row) * K_DIM + f2 * 2) =
            make_float2(unpk_lo(pp), unpk_hi(pp));
      }
    }
  }
}

extern "C" void kernel_launch(void* const* d_in, const int* in_sizes, int n_in,
                              void* d_out, int out_size, void* d_ws, size_t ws_size,
                              hipStream_t stream) {
  const float* Yh  = (const float*)d_in[0];
  const float* u   = (const float*)d_in[1];
  const float* W1  = (const float*)d_in[2];
  const float* b1  = (const float*)d_in[3];
  const float* W2  = (const float*)d_in[4];
  const float* b2  = (const float*)d_in[5];
  const float* Wa  = (const float*)d_in[6];
  const float* ba  = (const float*)d_in[7];
  const float* Wb  = (const float*)d_in[8];
  const float* bb  = (const float*)d_in[9];
  const float* Wd1 = (const float*)d_in[10];
  const float* bd1 = (const float*)d_in[11];
  const float* Wd2 = (const float*)d_in[12];
  const float* bd2 = (const float*)d_in[13];

  bf16_t* ws   = (bf16_t*)d_ws;
  bf16_t* Wp1  = ws;                  // 6*256*32 = 49152 elems
  bf16_t* Wp2  = Wp1 + 49152;         // 8*256*32 = 65536
  bf16_t* Wpab = Wp2 + 65536;         // 8*64*32  = 16384 (interleaved a/b)
  bf16_t* Wpd1 = Wpab + 16384;        // 1*256*32 = 8192
  bf16_t* Wpd2 = Wpd1 + 8192;         // 8*192*32 = 49152

  float* outRecon = (float*)d_out;
  float* outAlpha = outRecon + (size_t)N_ROWS * D_IN;
  float* outBeta  = outAlpha + (size_t)N_ROWS * K_DIM;
  float* outPi    = outBeta  + (size_t)N_ROWS * K_DIM;

  pack_b_kernel<<<192, 256, 0, stream>>>(W1, Wp1, 162, 256, 256, 6);
  pack_b_kernel<<<256, 256, 0, stream>>>(W2, Wp2, 256, 256, 256, 8);
  pack_ab_kernel<<<64, 256, 0, stream>>>(Wa, Wb, Wpab);
  pack_b_kernel<<<32, 256, 0, stream>>>(Wd1, Wpd1, 30, 256, 256, 1);
  pack_b_kernel<<<192, 256, 0, stream>>>(Wd2, Wpd2, 256, 162, 192, 8);

  usdn_fused<<<N_ROWS / ROWS, NTHR, 0, stream>>>(Yh, u, b1, b2, ba, bb, bd1, bd2,
                                                 Wp1, Wp2, Wpab, Wpd1, Wpd2,
                                                 outRecon, outAlpha, outBeta, outPi);
}